// Round 5
// baseline (77.837 us; speedup 1.0000x reference)
//
#include <hip/hip_runtime.h>
#include <hip/hip_bf16.h>

#define Bn 4
#define Nn 512
#define Tn 10
#define Fn 516      // N + 4
#define MH 128      // MSG_HID
#define MD 32       // MSG_DIM
#define UH 128      // UPD_HID
#define OD 4        // OUT_DIM

#define JSPLIT 64
#define JPB (Nn / JSPLIT)   // 8 j's per block

typedef __attribute__((ext_vector_type(4))) short short4v;  // 4 bf16 = 2 VGPRs
typedef __attribute__((ext_vector_type(8))) short short8v;
typedef __attribute__((ext_vector_type(4))) float floatx4;

static __device__ inline unsigned pk2(float a, float b) {
  union { __hip_bfloat162 h; unsigned u; } cv;
  cv.h = __float22bfloat162_rn(make_float2(a, b));
  return cv.u;
}
static __device__ inline short4v pack4(float a, float b, float c, float d) {
  union { short4v s; unsigned u[2]; } cv;
  cv.u[0] = pk2(a, b);
  cv.u[1] = pk2(c, d);
  return cv.s;
}

// K=16 bf16 MFMA. A/B frag: lane(ln,q) elem e -> k = 4q+e. D: row m = 4q+r, col n = ln.
#if __has_builtin(__builtin_amdgcn_mfma_f32_16x16x16bf16_1k)
static __device__ inline floatx4 MFMA16(short4v a, short4v b, floatx4 c) {
  return __builtin_amdgcn_mfma_f32_16x16x16bf16_1k(a, b, c, 0, 0, 0);
}
#else
// Fallback: K=16 data in elems 0-3 of the K=32 op pairs k-wise; zero tail is exact.
static __device__ inline floatx4 MFMA16(short4v a, short4v b, floatx4 c) {
  short8v a8 = {a[0], a[1], a[2], a[3], 0, 0, 0, 0};
  short8v b8 = {b[0], b[1], b[2], b[3], 0, 0, 0, 0};
  return __builtin_amdgcn_mfma_f32_16x16x32_bf16(a8, b8, c, 0, 0, 0);
}
#endif

// ---------------- Kernel A: Abase[b*N+j][128] = mb1 + sum_{t,c<4} x[b,j,t,c]*mW1[5t+c][:]
__global__ __launch_bounds__(128) void kA(const float* __restrict__ x,
                                          const float* __restrict__ mW1,
                                          const float* __restrict__ mb1,
                                          float* __restrict__ Abase) {
  int bj = blockIdx.x;
  int k  = threadIdx.x;
  const float* xr = x + (size_t)bj * Tn * Fn;
  float acc = mb1[k];
#pragma unroll
  for (int t = 0; t < Tn; ++t)
#pragma unroll
    for (int c = 0; c < 4; ++c)
      acc = fmaf(xr[t * Fn + c], mW1[(t * 5 + c) * MH + k], acc);
  Abase[(size_t)bj * MH + k] = acc;
}

// ---------------- Kernel B: register-chained MFMA pair-MLP, 16-i waves for max TLP.
// GEMM1: P[khid][i'] = W1e^T(128x16) . E^T(16x16) + Abase   (K = t, padded 10->16)
// GEMM2: msum[i'][c] += relu(P)^T . W2                      (K = khid, 8 x 16)
__global__ __launch_bounds__(256, 8) void kB(const float* __restrict__ x,
                                             const float* __restrict__ Abase,
                                             const float* __restrict__ mW1,
                                             const float* __restrict__ mW2,
                                             float* __restrict__ msum) {
  const int bx    = blockIdx.x;              // B * 8 * JSPLIT = 2048
  const int jsp   = bx & (JSPLIT - 1);
  const int itile = (bx >> 6) & 7;           // 64-i tile
  const int b     = bx >> 9;
  const int tid   = threadIdx.x;
  const int w     = tid >> 6;                // wave -> 16-wide i slice
  const int l     = tid & 63;
  const int ln    = l & 15;
  const int q     = l >> 4;
  const int ibase = itile * 64 + w * 16;

  __shared__ float ciL[JPB][MH];             // 4 KB: Abase rows for this block's 8 j's

  // ---- cooperative stage: 8 rows x 128 floats, contiguous in Abase
  {
    const float4* src = (const float4*)(Abase + (size_t)(b * Nn + jsp * JPB) * MH);
    float4* dst = (float4*)&ciL[0][0];
#pragma unroll
    for (int u = 0; u < 2; ++u)
      dst[tid + u * 256] = src[tid + u * 256];
  }

  // ---- A1 frags: A[m=khid][k=t] = W1e^T, zero for t>=10
  short4v A1[8];
#pragma unroll
  for (int mt = 0; mt < 8; ++mt) {
    float v[4];
#pragma unroll
    for (int e = 0; e < 4; ++e) {
      int t = q * 4 + e;
      v[e] = (t < Tn) ? mW1[(t * 5 + 4) * MH + mt * 16 + ln] : 0.f;
    }
    A1[mt] = pack4(v[0], v[1], v[2], v[3]);
  }
  // ---- B2 frags: B[k=khid][n=c] = W2 (8 k-tiles x 2 c-tiles)
  short4v B2[8][2];
#pragma unroll
  for (int kt = 0; kt < 8; ++kt)
#pragma unroll
    for (int ct = 0; ct < 2; ++ct) {
      float v[4];
#pragma unroll
      for (int e = 0; e < 4; ++e)
        v[e] = mW2[(kt * 16 + q * 4 + e) * MD + ct * 16 + ln];
      B2[kt][ct] = pack4(v[0], v[1], v[2], v[3]);
    }

  floatx4 acc[2];
  acc[0] = (floatx4)0.f;
  acc[1] = (floatx4)0.f;

  __syncthreads();

#pragma unroll 2
  for (int jj = 0; jj < JPB; ++jj) {
    const int j = jsp * JPB + jj;

    // E frag: B[k=t][n=i'], zero t>=10 (coalesced 64B over ln)
    const float* xp = x + (size_t)(b * Nn + j) * Tn * Fn + 4 + ibase;
    float v[4];
#pragma unroll
    for (int e = 0; e < 4; ++e) {
      int t = q * 4 + e;
      v[e] = (t < Tn) ? xp[(size_t)t * Fn + ln] : 0.f;
    }
    short4v B1 = pack4(v[0], v[1], v[2], v[3]);

    // Chained GEMM1 -> relu/pack -> GEMM2, C-input from LDS.
    // D1 row (4q+r) == A2 k (4q+e): the packed D1 tile IS the GEMM2 A-frag.
#pragma unroll
    for (int mt = 0; mt < 8; ++mt) {
      floatx4 ci = *(const floatx4*)&ciL[jj][mt * 16 + q * 4];
      floatx4 d0 = MFMA16(A1[mt], B1, ci);
      short4v pa = pack4(fmaxf(d0[0], 0.f), fmaxf(d0[1], 0.f),
                         fmaxf(d0[2], 0.f), fmaxf(d0[3], 0.f));
      acc[0] = MFMA16(pa, B2[mt][0], acc[0]);
      acc[1] = MFMA16(pa, B2[mt][1], acc[1]);
    }
  }

  // ---- accumulate into msum: i = ibase + 4q + r, c = ct*16 + ln
#pragma unroll
  for (int ct = 0; ct < 2; ++ct)
#pragma unroll
    for (int r = 0; r < 4; ++r) {
      int i = ibase + q * 4 + r;
      int c = ct * 16 + ln;
      atomicAdd(&msum[(size_t)(b * Nn + i) * MD + c], acc[ct][r]);
    }
}

// ---------------- Kernel C: per (b,i) final MLP 36 -> 128 -> 4
__global__ __launch_bounds__(128) void kC(const float* __restrict__ x,
                                          const float* __restrict__ msum,
                                          const float* __restrict__ mb2,
                                          const float* __restrict__ iW1,
                                          const float* __restrict__ ib1,
                                          const float* __restrict__ iW2,
                                          const float* __restrict__ ib2,
                                          float* __restrict__ out) {
  int bi = blockIdx.x;
  int k  = threadIdx.x;
  __shared__ float red[UH][OD];

  const float* ms = msum + (size_t)bi * MD;
  const float* nf = x + ((size_t)bi * Tn + (Tn - 1)) * Fn;

  float a = ib1[k];
#pragma unroll
  for (int c = 0; c < MD; ++c)
    a = fmaf(ms[c] + (float)Nn * mb2[c], iW1[c * UH + k], a);
#pragma unroll
  for (int c = 0; c < 4; ++c)
    a = fmaf(nf[c], iW1[(MD + c) * UH + k], a);
  a = fmaxf(a, 0.f);
#pragma unroll
  for (int c = 0; c < OD; ++c) red[k][c] = a * iW2[k * OD + c];
  __syncthreads();

  if (k < OD) {
    float s = ib2[k];
    for (int kk = 0; kk < UH; ++kk) s += red[kk][k];
    out[(size_t)bi * OD + k] = s;
  }
}

extern "C" void kernel_launch(void* const* d_in, const int* in_sizes, int n_in,
                              void* d_out, int out_size, void* d_ws, size_t ws_size,
                              hipStream_t stream) {
  const float* x   = (const float*)d_in[0];
  const float* mW1 = (const float*)d_in[1];
  const float* mb1 = (const float*)d_in[2];
  const float* mW2 = (const float*)d_in[3];
  const float* mb2 = (const float*)d_in[4];
  const float* iW1 = (const float*)d_in[5];
  const float* ib1 = (const float*)d_in[6];
  const float* iW2 = (const float*)d_in[7];
  const float* ib2 = (const float*)d_in[8];
  float* out = (float*)d_out;

  float* Abase = (float*)d_ws;                         // B*N*128 floats
  float* msum  = Abase + (size_t)Bn * Nn * MH;         // B*N*32 floats

  hipMemsetAsync(msum, 0, (size_t)Bn * Nn * MD * sizeof(float), stream);

  kA<<<Bn * Nn, 128, 0, stream>>>(x, mW1, mb1, Abase);
  kB<<<Bn * 8 * JSPLIT, 256, 0, stream>>>(x, Abase, mW1, mW2, msum);
  kC<<<Bn * Nn, 128, 0, stream>>>(x, msum, mb2, iW1, ib1, iW2, ib2, out);
}